// Round 1
// baseline (830.353 us; speedup 1.0000x reference)
//
#include <hip/hip_runtime.h>

#define B_ 32
#define N_ 4096
#define D_ 512
#define S_ 8
#define ITERS_ 3
#define CHUNKS 16          // fused-pass chunks per batch (grid = 32*CHUNKS blocks)
#define RPC (N_/CHUNKS)    // rows per chunk = 256

// ---------------------------------------------------------------- utilities
__device__ __forceinline__ float sigmoid_f(float x) {
    return 1.0f / (1.0f + __expf(-x));
}
__device__ __forceinline__ float tanh_f(float x) {
    float e = __expf(2.0f * x);          // inf-safe: e=inf -> 1, e=0 -> -1
    return 1.0f - 2.0f / (e + 1.0f);
}

// ---------------------------------------------------------------- slot init
__global__ void k_init_slots(const float* __restrict__ noise,
                             const float* __restrict__ mu,
                             const float* __restrict__ sg,
                             float* __restrict__ slots) {
    int i = blockIdx.x * 256 + threadIdx.x;       // < B_*S_*D_ = 131072
    int r = i & (S_ * D_ - 1);
    slots[i] = fmaf(sg[r], noise[i], mu[r]);
}

// ---------------------------------------------------------------- LayerNorm rows (D=512), one wave per row
__global__ void k_ln_rows(const float* __restrict__ in,
                          const float* __restrict__ g,
                          const float* __restrict__ bb,
                          float* __restrict__ out) {
    int wid = threadIdx.x >> 6, lane = threadIdx.x & 63;
    int row = blockIdx.x * 4 + wid;
    const float4* in4 = (const float4*)(in + (size_t)row * D_);
    float4 xlo = in4[lane], xhi = in4[64 + lane];
    float s1 = xlo.x + xlo.y + xlo.z + xlo.w + xhi.x + xhi.y + xhi.z + xhi.w;
    float s2 = xlo.x*xlo.x; s2 = fmaf(xlo.y,xlo.y,s2); s2 = fmaf(xlo.z,xlo.z,s2); s2 = fmaf(xlo.w,xlo.w,s2);
    s2 = fmaf(xhi.x,xhi.x,s2); s2 = fmaf(xhi.y,xhi.y,s2); s2 = fmaf(xhi.z,xhi.z,s2); s2 = fmaf(xhi.w,xhi.w,s2);
#pragma unroll
    for (int off = 32; off > 0; off >>= 1) {
        s1 += __shfl_xor(s1, off, 64);
        s2 += __shfl_xor(s2, off, 64);
    }
    float mean = s1 * (1.0f / D_);
    float var  = s2 * (1.0f / D_) - mean * mean;
    float rs   = rsqrtf(var + 1e-5f);
    const float4* g4 = (const float4*)g;
    const float4* b4 = (const float4*)bb;
    float4 glo = g4[lane], ghi = g4[64 + lane];
    float4 blo = b4[lane], bhi = b4[64 + lane];
    float4 olo, ohi;
    olo.x = fmaf((xlo.x - mean) * rs, glo.x, blo.x);
    olo.y = fmaf((xlo.y - mean) * rs, glo.y, blo.y);
    olo.z = fmaf((xlo.z - mean) * rs, glo.z, blo.z);
    olo.w = fmaf((xlo.w - mean) * rs, glo.w, blo.w);
    ohi.x = fmaf((xhi.x - mean) * rs, ghi.x, bhi.x);
    ohi.y = fmaf((xhi.y - mean) * rs, ghi.y, bhi.y);
    ohi.z = fmaf((xhi.z - mean) * rs, ghi.z, bhi.z);
    ohi.w = fmaf((xhi.w - mean) * rs, ghi.w, bhi.w);
    float4* o4 = (float4*)(out + (size_t)row * D_);
    o4[lane] = olo; o4[64 + lane] = ohi;
}

// ---------------------------------------------------------------- small GEMM
// C[M,N] = A[M,K] @ (WT ? W[N,K]^T : W[K,N])  (+bias) (+relu) (+residual)
// tile: 64 rows x 32 cols, 256 threads, each 4x2 micro-tile, K chunked by 64.
template<int WT>
__global__ __launch_bounds__(256) void k_gemm(const float* __restrict__ A,
                                              const float* __restrict__ W,
                                              const float* __restrict__ bias,
                                              const float* __restrict__ resid,
                                              float* __restrict__ C,
                                              int M, int N, int K, int relu) {
    __shared__ float As[64][68];   // [k][m], padded
    __shared__ float Ws[64][36];   // [k][n], padded
    int t  = threadIdx.x;
    int bm = blockIdx.y * 64, bn = blockIdx.x * 32;
    int tm = t >> 4, tn = t & 15;
    float acc[4][2] = {{0.f,0.f},{0.f,0.f},{0.f,0.f},{0.f,0.f}};

    for (int kk = 0; kk < K; kk += 64) {
        __syncthreads();
        // stage A: 64 rows x 64 k (transpose to k-major)
#pragma unroll
        for (int r = 0; r < 4; ++r) {
            int flat = t * 4 + r * 1024;
            int m = flat >> 6, k = flat & 63;
            float4 a4 = *(const float4*)(A + (size_t)(bm + m) * K + kk + k);
            As[k + 0][m] = a4.x; As[k + 1][m] = a4.y;
            As[k + 2][m] = a4.z; As[k + 3][m] = a4.w;
        }
        if (WT) {
#pragma unroll
            for (int r = 0; r < 2; ++r) {
                int flat = t * 4 + r * 1024;
                int n = flat >> 6, k = flat & 63;
                float4 w4 = *(const float4*)(W + (size_t)(bn + n) * K + kk + k);
                Ws[k + 0][n] = w4.x; Ws[k + 1][n] = w4.y;
                Ws[k + 2][n] = w4.z; Ws[k + 3][n] = w4.w;
            }
        } else {
#pragma unroll
            for (int r = 0; r < 2; ++r) {
                int flat = t * 4 + r * 1024;
                int k = flat >> 5, n = flat & 31;
                float4 w4 = *(const float4*)(W + (size_t)(kk + k) * N + bn + n);
                *(float4*)&Ws[k][n] = w4;
            }
        }
        __syncthreads();
#pragma unroll
        for (int k = 0; k < 64; ++k) {
            float4 a = *(const float4*)&As[k][tm << 2];
            float2 w = *(const float2*)&Ws[k][tn << 1];
            acc[0][0] = fmaf(a.x, w.x, acc[0][0]); acc[0][1] = fmaf(a.x, w.y, acc[0][1]);
            acc[1][0] = fmaf(a.y, w.x, acc[1][0]); acc[1][1] = fmaf(a.y, w.y, acc[1][1]);
            acc[2][0] = fmaf(a.z, w.x, acc[2][0]); acc[2][1] = fmaf(a.z, w.y, acc[2][1]);
            acc[3][0] = fmaf(a.w, w.x, acc[3][0]); acc[3][1] = fmaf(a.w, w.y, acc[3][1]);
        }
    }
#pragma unroll
    for (int i = 0; i < 4; ++i) {
#pragma unroll
        for (int j = 0; j < 2; ++j) {
            int row = bm + (tm << 2) + i;
            int col = bn + (tn << 1) + j;
            float v = acc[i][j];
            if (bias)  v += bias[col];
            if (relu)  v = fmaxf(v, 0.0f);
            if (resid) v += resid[(size_t)row * N + col];
            C[(size_t)row * N + col] = v;
        }
    }
}

// ---------------------------------------------------------------- fused pass
// per row of inputs: LN -> logits(8) -> softmax(+EPS renorm) -> u0 accumulation
__global__ __launch_bounds__(256) void k_attn(const float* __restrict__ xin,
                                              const float* __restrict__ gv,
                                              const float* __restrict__ bv,
                                              const float* __restrict__ qk,
                                              float* __restrict__ part) {
    __shared__ float qks[S_ * D_];
    __shared__ float u0s[S_ * D_];
    int c = blockIdx.x, b = blockIdx.y;
    int wid = threadIdx.x >> 6, lane = threadIdx.x & 63;
    {
        const float4* src = (const float4*)(qk + (size_t)b * S_ * D_);
        float4* dst = (float4*)qks;
        for (int i = threadIdx.x; i < 1024; i += 256) dst[i] = src[i];
    }
    __syncthreads();
    const float4* g4 = (const float4*)gv;
    const float4* b4 = (const float4*)bv;
    float4 glo = g4[lane], ghi = g4[64 + lane];
    float4 blo = b4[lane], bhi = b4[64 + lane];
    float4 alo[8], ahi[8];
#pragma unroll
    for (int s = 0; s < 8; ++s) {
        alo[s] = make_float4(0.f, 0.f, 0.f, 0.f);
        ahi[s] = make_float4(0.f, 0.f, 0.f, 0.f);
    }
    const float cnorm = 1.0f / (1.0f + 8.0f * 1e-8f);
    const float eadd  = 1e-8f * cnorm;

    for (int i = wid; i < RPC; i += 4) {
        int n = c * RPC + i;
        const float4* x4 = (const float4*)(xin + ((size_t)b * N_ + n) * D_);
        float4 xlo = x4[lane], xhi = x4[64 + lane];
        // LN stats
        float s1 = xlo.x + xlo.y + xlo.z + xlo.w + xhi.x + xhi.y + xhi.z + xhi.w;
        float s2 = xlo.x*xlo.x; s2 = fmaf(xlo.y,xlo.y,s2); s2 = fmaf(xlo.z,xlo.z,s2); s2 = fmaf(xlo.w,xlo.w,s2);
        s2 = fmaf(xhi.x,xhi.x,s2); s2 = fmaf(xhi.y,xhi.y,s2); s2 = fmaf(xhi.z,xhi.z,s2); s2 = fmaf(xhi.w,xhi.w,s2);
#pragma unroll
        for (int off = 32; off > 0; off >>= 1) {
            s1 += __shfl_xor(s1, off, 64);
            s2 += __shfl_xor(s2, off, 64);
        }
        float mean = s1 * (1.0f / D_);
        float var  = s2 * (1.0f / D_) - mean * mean;
        float rs   = rsqrtf(var + 1e-5f);
        float4 hlo, hhi;
        hlo.x = fmaf((xlo.x - mean) * rs, glo.x, blo.x);
        hlo.y = fmaf((xlo.y - mean) * rs, glo.y, blo.y);
        hlo.z = fmaf((xlo.z - mean) * rs, glo.z, blo.z);
        hlo.w = fmaf((xlo.w - mean) * rs, glo.w, blo.w);
        hhi.x = fmaf((xhi.x - mean) * rs, ghi.x, bhi.x);
        hhi.y = fmaf((xhi.y - mean) * rs, ghi.y, bhi.y);
        hhi.z = fmaf((xhi.z - mean) * rs, ghi.z, bhi.z);
        hhi.w = fmaf((xhi.w - mean) * rs, ghi.w, bhi.w);
        // 8 slot logits (partial per lane)
        float dd[8];
#pragma unroll
        for (int s = 0; s < 8; ++s) {
            const float4 ql = *(const float4*)&qks[s * 512 + (lane << 2)];
            const float4 qh = *(const float4*)&qks[s * 512 + 256 + (lane << 2)];
            float tdot = hlo.x * ql.x;
            tdot = fmaf(hlo.y, ql.y, tdot); tdot = fmaf(hlo.z, ql.z, tdot); tdot = fmaf(hlo.w, ql.w, tdot);
            tdot = fmaf(hhi.x, qh.x, tdot); tdot = fmaf(hhi.y, qh.y, tdot);
            tdot = fmaf(hhi.z, qh.z, tdot); tdot = fmaf(hhi.w, qh.w, tdot);
            dd[s] = tdot;
        }
#pragma unroll
        for (int off = 32; off > 0; off >>= 1) {
#pragma unroll
            for (int s = 0; s < 8; ++s) dd[s] += __shfl_xor(dd[s], off, 64);
        }
        // softmax over 8 slots + EPS renorm
        float mx = dd[0];
#pragma unroll
        for (int s = 1; s < 8; ++s) mx = fmaxf(mx, dd[s]);
        float pp[8], psum = 0.f;
#pragma unroll
        for (int s = 0; s < 8; ++s) { pp[s] = __expf(dd[s] - mx); psum += pp[s]; }
        float ip = cnorm / psum;
#pragma unroll
        for (int s = 0; s < 8; ++s) {
            float a = fmaf(pp[s], ip, eadd);
            alo[s].x = fmaf(a, hlo.x, alo[s].x); alo[s].y = fmaf(a, hlo.y, alo[s].y);
            alo[s].z = fmaf(a, hlo.z, alo[s].z); alo[s].w = fmaf(a, hlo.w, alo[s].w);
            ahi[s].x = fmaf(a, hhi.x, ahi[s].x); ahi[s].y = fmaf(a, hhi.y, ahi[s].y);
            ahi[s].z = fmaf(a, hhi.z, ahi[s].z); ahi[s].w = fmaf(a, hhi.w, ahi[s].w);
        }
    }
    // cross-wave reduction into LDS
    for (int w = 0; w < 4; ++w) {
        if (wid == w) {
#pragma unroll
            for (int s = 0; s < 8; ++s) {
                float* p0 = &u0s[s * 512 + (lane << 2)];
                float* p1 = p0 + 256;
                if (w == 0) {
                    *(float4*)p0 = alo[s];
                    *(float4*)p1 = ahi[s];
                } else {
                    float4 v0 = *(float4*)p0;
                    v0.x += alo[s].x; v0.y += alo[s].y; v0.z += alo[s].z; v0.w += alo[s].w;
                    *(float4*)p0 = v0;
                    float4 v1 = *(float4*)p1;
                    v1.x += ahi[s].x; v1.y += ahi[s].y; v1.z += ahi[s].z; v1.w += ahi[s].w;
                    *(float4*)p1 = v1;
                }
            }
        }
        __syncthreads();
    }
    float4* d4 = (float4*)(part + ((size_t)(b * CHUNKS + c)) * (S_ * D_));
    const float4* s4 = (const float4*)u0s;
    for (int i = threadIdx.x; i < 1024; i += 256) d4[i] = s4[i];
}

// ---------------------------------------------------------------- reduce u0 partials
__global__ void k_reduce_u0(const float* __restrict__ part, float* __restrict__ u0) {
    int i = blockIdx.x * 256 + threadIdx.x;       // over 32768 float4
    int b = i >> 10, r = i & 1023;
    const float4* p4 = (const float4*)part;
    float4 acc = make_float4(0.f, 0.f, 0.f, 0.f);
#pragma unroll
    for (int c = 0; c < CHUNKS; ++c) {
        float4 v = p4[(size_t)(b * CHUNKS + c) * 1024 + r];
        acc.x += v.x; acc.y += v.y; acc.z += v.z; acc.w += v.w;
    }
    ((float4*)u0)[i] = acc;
}

// ---------------------------------------------------------------- GRU cell (elementwise)
__global__ void k_gru(const float* __restrict__ gi, const float* __restrict__ gh,
                      const float* __restrict__ sp, float* __restrict__ out) {
    int i = blockIdx.x * 256 + threadIdx.x;       // < 131072
    int row = i >> 9, d = i & 511;
    const float* gib = gi + (size_t)row * 1536;
    const float* ghb = gh + (size_t)row * 1536;
    float gir = gib[d], giz = gib[d + 512], gin = gib[d + 1024];
    float ghr = ghb[d], ghz = ghb[d + 512], ghn = ghb[d + 1024];
    float r = sigmoid_f(gir + ghr);
    float z = sigmoid_f(giz + ghz);
    float nn = tanh_f(fmaf(r, ghn, gin));
    float s = sp[i];
    out[i] = fmaf(1.0f - z, nn, z * s);
}

// ---------------------------------------------------------------- launch
extern "C" void kernel_launch(void* const* d_in, const int* in_sizes, int n_in,
                              void* d_out, int out_size, void* d_ws, size_t ws_size,
                              hipStream_t stream) {
    const float* inputs  = (const float*)d_in[0];
    const float* noise   = (const float*)d_in[1];
    const float* mu      = (const float*)d_in[2];
    const float* sg      = (const float*)d_in[3];
    const float* ln_in_g = (const float*)d_in[4];
    const float* ln_in_b = (const float*)d_in[5];
    const float* ln_s_g  = (const float*)d_in[6];
    const float* ln_s_b  = (const float*)d_in[7];
    const float* wq      = (const float*)d_in[8];
    const float* wk      = (const float*)d_in[9];
    const float* wv      = (const float*)d_in[10];
    const float* w_ih    = (const float*)d_in[11];
    const float* w_hh    = (const float*)d_in[12];
    const float* b_ih    = (const float*)d_in[13];
    const float* b_hh    = (const float*)d_in[14];
    const float* ln_m_g  = (const float*)d_in[15];
    const float* ln_m_b  = (const float*)d_in[16];
    const float* w1      = (const float*)d_in[17];
    const float* b1      = (const float*)d_in[18];
    const float* w2      = (const float*)d_in[19];
    const float* b2      = (const float*)d_in[20];

    float* ws = (float*)d_ws;
    const int SLOT = B_ * S_ * D_;                 // 131072
    float* slots  = ws;
    float* sn     = ws + (size_t)SLOT;
    float* q      = ws + (size_t)2 * SLOT;
    float* qk     = ws + (size_t)3 * SLOT;
    float* u0     = ws + (size_t)4 * SLOT;
    float* upd    = ws + (size_t)5 * SLOT;
    float* slots2 = ws + (size_t)6 * SLOT;
    float* h0     = ws + (size_t)7 * SLOT;
    float* h      = ws + (size_t)8 * SLOT;
    float* gi     = ws + (size_t)9 * SLOT;         // 3*SLOT
    float* gh     = gi + (size_t)3 * SLOT;         // 3*SLOT
    float* part   = gh + (size_t)3 * SLOT;         // CHUNKS*SLOT/..  (B*CHUNKS*4096)

    k_init_slots<<<512, 256, 0, stream>>>(noise, mu, sg, slots);

    for (int it = 0; it < ITERS_; ++it) {
        // sn = LN(slots)
        k_ln_rows<<<64, 256, 0, stream>>>(slots, ln_s_g, ln_s_b, sn);
        // q = sn @ wq^T
        k_gemm<1><<<dim3(16, 4), 256, 0, stream>>>(sn, wq, nullptr, nullptr, q, 256, 512, 512, 0);
        // qk = q @ wk   (wk is K x N)
        k_gemm<0><<<dim3(16, 4), 256, 0, stream>>>(q, wk, nullptr, nullptr, qk, 256, 512, 512, 0);
        // fused: LN(inputs) -> logits -> softmax -> u0 partials
        k_attn<<<dim3(CHUNKS, B_), 256, 0, stream>>>(inputs, ln_in_g, ln_in_b, qk, part);
        k_reduce_u0<<<128, 256, 0, stream>>>(part, u0);
        // updates = u0 @ wv^T
        k_gemm<1><<<dim3(16, 4), 256, 0, stream>>>(u0, wv, nullptr, nullptr, upd, 256, 512, 512, 0);
        // gi = updates @ w_ih^T + b_ih ; gh = slots @ w_hh^T + b_hh
        k_gemm<1><<<dim3(48, 4), 256, 0, stream>>>(upd, w_ih, b_ih, nullptr, gi, 256, 1536, 512, 0);
        k_gemm<1><<<dim3(48, 4), 256, 0, stream>>>(slots, w_hh, b_hh, nullptr, gh, 256, 1536, 512, 0);
        // GRU -> slots2
        k_gru<<<512, 256, 0, stream>>>(gi, gh, slots, slots2);
        // h0 = LN(slots2); h = relu(h0 @ w1^T + b1); out = slots2 + h @ w2^T + b2
        k_ln_rows<<<64, 256, 0, stream>>>(slots2, ln_m_g, ln_m_b, h0);
        k_gemm<1><<<dim3(16, 4), 256, 0, stream>>>(h0, w1, b1, nullptr, h, 256, 512, 512, 1);
        float* dst = (it == ITERS_ - 1) ? (float*)d_out : slots;
        k_gemm<1><<<dim3(16, 4), 256, 0, stream>>>(h, w2, b2, slots2, dst, 256, 512, 512, 0);
    }
}

// Round 2
// 812.620 us; speedup vs baseline: 1.0218x; 1.0218x over previous
//
#include <hip/hip_runtime.h>

#define B_ 32
#define N_ 4096
#define D_ 512
#define S_ 8
#define ITERS_ 3
#define CH 32              // attention chunks per batch
#define RPC (N_/CH)        // rows per chunk = 128

__device__ __forceinline__ float sigmoid_f(float x) {
    return 1.0f / (1.0f + __expf(-x));
}
__device__ __forceinline__ float tanh_f(float x) {
    float e = __expf(2.0f * x);
    return 1.0f - 2.0f / (e + 1.0f);
}

// ---------------------------------------------------------------- slot init (+ LN stats per row)
__global__ __launch_bounds__(256) void k_init(const float* __restrict__ noise,
                                              const float* __restrict__ mu,
                                              const float* __restrict__ sg,
                                              float* __restrict__ slots,
                                              float* __restrict__ stats) {
    int wid = threadIdx.x >> 6, lane = threadIdx.x & 63;
    int row = blockIdx.x * 4 + wid;                       // 0..255
    const float4* nz = (const float4*)(noise + (size_t)row * D_);
    const float4* m4 = (const float4*)(mu + (size_t)(row & 7) * D_);
    const float4* s4 = (const float4*)(sg + (size_t)(row & 7) * D_);
    float4 v0 = nz[lane], v1 = nz[64 + lane];
    float4 a0 = m4[lane], a1 = m4[64 + lane];
    float4 c0 = s4[lane], c1 = s4[64 + lane];
    v0.x = fmaf(c0.x, v0.x, a0.x); v0.y = fmaf(c0.y, v0.y, a0.y);
    v0.z = fmaf(c0.z, v0.z, a0.z); v0.w = fmaf(c0.w, v0.w, a0.w);
    v1.x = fmaf(c1.x, v1.x, a1.x); v1.y = fmaf(c1.y, v1.y, a1.y);
    v1.z = fmaf(c1.z, v1.z, a1.z); v1.w = fmaf(c1.w, v1.w, a1.w);
    float4* o4 = (float4*)(slots + (size_t)row * D_);
    o4[lane] = v0; o4[64 + lane] = v1;
    float s1 = v0.x + v0.y + v0.z + v0.w + v1.x + v1.y + v1.z + v1.w;
    float s2 = v0.x*v0.x; s2 = fmaf(v0.y,v0.y,s2); s2 = fmaf(v0.z,v0.z,s2); s2 = fmaf(v0.w,v0.w,s2);
    s2 = fmaf(v1.x,v1.x,s2); s2 = fmaf(v1.y,v1.y,s2); s2 = fmaf(v1.z,v1.z,s2); s2 = fmaf(v1.w,v1.w,s2);
#pragma unroll
    for (int off = 32; off > 0; off >>= 1) {
        s1 += __shfl_xor(s1, off, 64);
        s2 += __shfl_xor(s2, off, 64);
    }
    if (lane == 0) {
        float mean = s1 * (1.0f / D_);
        float var  = s2 * (1.0f / D_) - mean * mean;
        stats[row * 2]     = mean;
        stats[row * 2 + 1] = rsqrtf(var + 1e-5f);
    }
}

// ---------------------------------------------------------------- small GEMM
// WT=0: C = A[M,K] @ W[K,N]; WT=1: C = A[M,K] @ W[N,K]^T; WT=2: C = A[K,M]^T @ W[K,N]
// LNA=1: A read through LayerNorm (stats per row + g/b per k)
template<int WT, int LNA>
__global__ __launch_bounds__(256) void k_gemm(const float* __restrict__ A,
                                              const float* __restrict__ W,
                                              const float* __restrict__ bias,
                                              const float* __restrict__ resid,
                                              float* __restrict__ C,
                                              int M, int N, int K, int relu,
                                              const float* __restrict__ stats,
                                              const float* __restrict__ lng,
                                              const float* __restrict__ lnb) {
    __shared__ float As[64][68];   // [k][m], padded
    __shared__ float Ws[64][36];   // [k][n], padded
    int t  = threadIdx.x;
    int bm = blockIdx.y * 64, bn = blockIdx.x * 32;
    int tm = t >> 4, tn = t & 15;
    float acc[4][2] = {{0.f,0.f},{0.f,0.f},{0.f,0.f},{0.f,0.f}};

    for (int kk = 0; kk < K; kk += 64) {
        __syncthreads();
        if (WT == 2) {
            // A is (K, M): As[k][m] from rows of A (contiguous along m)
#pragma unroll
            for (int r = 0; r < 4; ++r) {
                int idx = t + r * 256;            // 0..1023 float4 slots
                int k = idx >> 4, m4 = idx & 15;
                float4 a4 = *(const float4*)(A + (size_t)(kk + k) * M + bm + (m4 << 2));
                *(float4*)&As[k][m4 << 2] = a4;
            }
        } else {
#pragma unroll
            for (int r = 0; r < 4; ++r) {
                int flat = t * 4 + r * 1024;
                int m = flat >> 6, k = flat & 63;
                float4 a4 = *(const float4*)(A + (size_t)(bm + m) * K + kk + k);
                if (LNA) {
                    float mean = stats[(bm + m) * 2];
                    float rs   = stats[(bm + m) * 2 + 1];
                    float4 g4 = *(const float4*)(lng + kk + k);
                    float4 b4 = *(const float4*)(lnb + kk + k);
                    a4.x = fmaf((a4.x - mean) * rs, g4.x, b4.x);
                    a4.y = fmaf((a4.y - mean) * rs, g4.y, b4.y);
                    a4.z = fmaf((a4.z - mean) * rs, g4.z, b4.z);
                    a4.w = fmaf((a4.w - mean) * rs, g4.w, b4.w);
                }
                As[k + 0][m] = a4.x; As[k + 1][m] = a4.y;
                As[k + 2][m] = a4.z; As[k + 3][m] = a4.w;
            }
        }
        if (WT == 1) {
#pragma unroll
            for (int r = 0; r < 2; ++r) {
                int flat = t * 4 + r * 1024;
                int n = flat >> 6, k = flat & 63;
                float4 w4 = *(const float4*)(W + (size_t)(bn + n) * K + kk + k);
                Ws[k + 0][n] = w4.x; Ws[k + 1][n] = w4.y;
                Ws[k + 2][n] = w4.z; Ws[k + 3][n] = w4.w;
            }
        } else {
#pragma unroll
            for (int r = 0; r < 2; ++r) {
                int flat = t * 4 + r * 1024;
                int k = flat >> 5, n = flat & 31;
                float4 w4 = *(const float4*)(W + (size_t)(kk + k) * N + bn + n);
                *(float4*)&Ws[k][n] = w4;
            }
        }
        __syncthreads();
#pragma unroll
        for (int k = 0; k < 64; ++k) {
            float4 a = *(const float4*)&As[k][tm << 2];
            float2 w = *(const float2*)&Ws[k][tn << 1];
            acc[0][0] = fmaf(a.x, w.x, acc[0][0]); acc[0][1] = fmaf(a.x, w.y, acc[0][1]);
            acc[1][0] = fmaf(a.y, w.x, acc[1][0]); acc[1][1] = fmaf(a.y, w.y, acc[1][1]);
            acc[2][0] = fmaf(a.z, w.x, acc[2][0]); acc[2][1] = fmaf(a.z, w.y, acc[2][1]);
            acc[3][0] = fmaf(a.w, w.x, acc[3][0]); acc[3][1] = fmaf(a.w, w.y, acc[3][1]);
        }
    }
#pragma unroll
    for (int i = 0; i < 4; ++i) {
#pragma unroll
        for (int j = 0; j < 2; ++j) {
            int row = bm + (tm << 2) + i;
            int col = bn + (tn << 1) + j;
            float v = acc[i][j];
            if (bias)  v += bias[col];
            if (relu)  v = fmaxf(v, 0.0f);
            if (resid) v += resid[(size_t)row * N + col];
            C[(size_t)row * N + col] = v;
        }
    }
}

// ---------------------------------------------------------------- fused attention pass
// per input row: LN -> 8 logits (qk in regs) -> fold-reduce -> softmax -> u0 accumulation
__global__ __launch_bounds__(256, 2) void k_attn(const float* __restrict__ xin,
                                                 const float* __restrict__ gv,
                                                 const float* __restrict__ bv,
                                                 const float* __restrict__ qk,
                                                 float* __restrict__ part) {
    __shared__ float u0s[S_ * D_];
    const int c = blockIdx.x, b = blockIdx.y;
    const int wid = threadIdx.x >> 6, lane = threadIdx.x & 63;

    float4 qlo[8], qhi[8];
    const float* qb = qk + (size_t)b * S_ * D_;
#pragma unroll
    for (int s = 0; s < 8; ++s) {
        qlo[s] = *(const float4*)(qb + s * 512 + (lane << 2));
        qhi[s] = *(const float4*)(qb + s * 512 + 256 + (lane << 2));
    }
    float4 glo = ((const float4*)gv)[lane], ghi = ((const float4*)gv)[64 + lane];
    float4 blo = ((const float4*)bv)[lane], bhi = ((const float4*)bv)[64 + lane];

    float4 alo[8], ahi[8];
#pragma unroll
    for (int s = 0; s < 8; ++s) {
        alo[s] = make_float4(0.f, 0.f, 0.f, 0.f);
        ahi[s] = make_float4(0.f, 0.f, 0.f, 0.f);
    }
    const float cnorm = 1.0f / (1.0f + 8.0f * 1e-8f);
    const float eadd  = 1e-8f * cnorm;
    const bool hb5 = (lane & 32) != 0, hb4 = (lane & 16) != 0, hb3 = (lane & 8) != 0;
    const int gbase = lane & 7;

    const float* xrow = xin + ((size_t)b * N_ + (size_t)c * RPC + wid) * D_;
    float4 x0lo = ((const float4*)xrow)[lane];
    float4 x0hi = ((const float4*)xrow)[64 + lane];
    const float* xr1 = xrow + 4 * D_;
    float4 x1lo = ((const float4*)xr1)[lane];
    float4 x1hi = ((const float4*)xr1)[64 + lane];

    for (int j = 0; j < RPC / 4; ++j) {
        // depth-2 prefetch (clamped)
        int jn = (j < RPC / 4 - 2) ? j + 2 : RPC / 4 - 1;
        const float* xn = xrow + (size_t)jn * 4 * D_;
        float4 nlo = ((const float4*)xn)[lane];
        float4 nhi = ((const float4*)xn)[64 + lane];

        // ---- LN stats
        float s1 = x0lo.x + x0lo.y + x0lo.z + x0lo.w + x0hi.x + x0hi.y + x0hi.z + x0hi.w;
        float s2 = x0lo.x*x0lo.x; s2 = fmaf(x0lo.y,x0lo.y,s2); s2 = fmaf(x0lo.z,x0lo.z,s2); s2 = fmaf(x0lo.w,x0lo.w,s2);
        s2 = fmaf(x0hi.x,x0hi.x,s2); s2 = fmaf(x0hi.y,x0hi.y,s2); s2 = fmaf(x0hi.z,x0hi.z,s2); s2 = fmaf(x0hi.w,x0hi.w,s2);
#pragma unroll
        for (int off = 32; off > 0; off >>= 1) {
            s1 += __shfl_xor(s1, off, 64);
            s2 += __shfl_xor(s2, off, 64);
        }
        float mean = s1 * (1.0f / D_);
        float var  = s2 * (1.0f / D_) - mean * mean;
        float rs   = rsqrtf(var + 1e-5f);
        float4 hlo, hhi;
        hlo.x = fmaf((x0lo.x - mean) * rs, glo.x, blo.x);
        hlo.y = fmaf((x0lo.y - mean) * rs, glo.y, blo.y);
        hlo.z = fmaf((x0lo.z - mean) * rs, glo.z, blo.z);
        hlo.w = fmaf((x0lo.w - mean) * rs, glo.w, blo.w);
        hhi.x = fmaf((x0hi.x - mean) * rs, ghi.x, bhi.x);
        hhi.y = fmaf((x0hi.y - mean) * rs, ghi.y, bhi.y);
        hhi.z = fmaf((x0hi.z - mean) * rs, ghi.z, bhi.z);
        hhi.w = fmaf((x0hi.w - mean) * rs, ghi.w, bhi.w);

        // ---- per-lane partial logits
        float dd[8];
#pragma unroll
        for (int s = 0; s < 8; ++s) {
            float td = hlo.x * qlo[s].x;
            td = fmaf(hlo.y, qlo[s].y, td); td = fmaf(hlo.z, qlo[s].z, td); td = fmaf(hlo.w, qlo[s].w, td);
            td = fmaf(hhi.x, qhi[s].x, td); td = fmaf(hhi.y, qhi[s].y, td);
            td = fmaf(hhi.z, qhi[s].z, td); td = fmaf(hhi.w, qhi[s].w, td);
            dd[s] = td;
        }
        // ---- fold reduction: lane ends with full logit for slot (lane>>3)&7
        float r4[4];
#pragma unroll
        for (int s = 0; s < 4; ++s) {
            float snd = hb5 ? dd[s] : dd[s + 4];
            float kp  = hb5 ? dd[s + 4] : dd[s];
            r4[s] = kp + __shfl_xor(snd, 32, 64);
        }
        float r2[2];
#pragma unroll
        for (int s = 0; s < 2; ++s) {
            float snd = hb4 ? r4[s] : r4[s + 2];
            float kp  = hb4 ? r4[s + 2] : r4[s];
            r2[s] = kp + __shfl_xor(snd, 16, 64);
        }
        float v;
        {
            float snd = hb3 ? r2[0] : r2[1];
            float kp  = hb3 ? r2[1] : r2[0];
            v = kp + __shfl_xor(snd, 8, 64);
        }
        v += __shfl_xor(v, 4, 64);
        v += __shfl_xor(v, 2, 64);
        v += __shfl_xor(v, 1, 64);
        // ---- softmax across slot groups (lane bits 3..5)
        float m = v;
        m = fmaxf(m, __shfl_xor(m, 8, 64));
        m = fmaxf(m, __shfl_xor(m, 16, 64));
        m = fmaxf(m, __shfl_xor(m, 32, 64));
        float p = __expf(v - m);
        float ssum = p;
        ssum += __shfl_xor(ssum, 8, 64);
        ssum += __shfl_xor(ssum, 16, 64);
        ssum += __shfl_xor(ssum, 32, 64);
        float amine = fmaf(p, cnorm / ssum, eadd);
        // ---- gather all 8 attention weights
        float av[8];
#pragma unroll
        for (int s = 0; s < 8; ++s) av[s] = __shfl(amine, (s << 3) | gbase, 64);
        // ---- accumulate u0
#pragma unroll
        for (int s = 0; s < 8; ++s) {
            alo[s].x = fmaf(av[s], hlo.x, alo[s].x); alo[s].y = fmaf(av[s], hlo.y, alo[s].y);
            alo[s].z = fmaf(av[s], hlo.z, alo[s].z); alo[s].w = fmaf(av[s], hlo.w, alo[s].w);
            ahi[s].x = fmaf(av[s], hhi.x, ahi[s].x); ahi[s].y = fmaf(av[s], hhi.y, ahi[s].y);
            ahi[s].z = fmaf(av[s], hhi.z, ahi[s].z); ahi[s].w = fmaf(av[s], hhi.w, ahi[s].w);
        }
        x0lo = x1lo; x0hi = x1hi; x1lo = nlo; x1hi = nhi;
    }

    // ---- cross-wave reduction into LDS
    for (int w = 0; w < 4; ++w) {
        if (wid == w) {
#pragma unroll
            for (int s = 0; s < 8; ++s) {
                float* p0 = &u0s[s * 512 + (lane << 2)];
                float* p1 = p0 + 256;
                if (w == 0) {
                    *(float4*)p0 = alo[s];
                    *(float4*)p1 = ahi[s];
                } else {
                    float4 v0 = *(float4*)p0;
                    v0.x += alo[s].x; v0.y += alo[s].y; v0.z += alo[s].z; v0.w += alo[s].w;
                    *(float4*)p0 = v0;
                    float4 v1 = *(float4*)p1;
                    v1.x += ahi[s].x; v1.y += ahi[s].y; v1.z += ahi[s].z; v1.w += ahi[s].w;
                    *(float4*)p1 = v1;
                }
            }
        }
        __syncthreads();
    }
    float4* d4 = (float4*)(part + ((size_t)(b * CH + c)) * (S_ * D_));
    const float4* s4 = (const float4*)u0s;
    for (int i = threadIdx.x; i < 1024; i += 256) d4[i] = s4[i];
}

// ---------------------------------------------------------------- reduce u0 partials
__global__ void k_reduce_u0(const float* __restrict__ part, float* __restrict__ u0) {
    int i = blockIdx.x * 256 + threadIdx.x;       // over 32768 float4
    int b = i >> 10, r = i & 1023;
    const float4* p4 = (const float4*)part;
    float4 acc = make_float4(0.f, 0.f, 0.f, 0.f);
#pragma unroll
    for (int c = 0; c < CH; ++c) {
        float4 v = p4[(size_t)(b * CH + c) * 1024 + r];
        acc.x += v.x; acc.y += v.y; acc.z += v.z; acc.w += v.w;
    }
    ((float4*)u0)[i] = acc;
}

// ---------------------------------------------------------------- P2: GRU + MLP + LN + qk_next
// one block = 2 slot rows; row-local chain entirely in LDS
__global__ __launch_bounds__(512) void k_p2(const float* __restrict__ gi,
                                            const float* __restrict__ gh,
                                            const float* __restrict__ slots,
                                            const float* __restrict__ w1, const float* __restrict__ b1,
                                            const float* __restrict__ w2, const float* __restrict__ b2,
                                            const float* __restrict__ wqkT,
                                            const float* __restrict__ ln_m_g, const float* __restrict__ ln_m_b,
                                            const float* __restrict__ ln_s_g, const float* __restrict__ ln_s_b,
                                            float* __restrict__ dst, float* __restrict__ qkout, int last) {
    __shared__ float s2s[2][512];
    __shared__ float t0s[2][512];
    __shared__ float hs[2][512];
    __shared__ float stat[4];
    const int t = threadIdx.x;
    const int wid = t >> 6, lane = t & 63;
    const int r0 = blockIdx.x * 2;

    // ---- GRU
#pragma unroll
    for (int j = 0; j < 2; ++j) {
        int flat = t + j * 512;
        int r = flat >> 9, d = flat & 511;
        size_t row = r0 + r;
        const float* gib = gi + row * 1536;
        const float* ghb = gh + row * 1536;
        float gir = gib[d], giz = gib[d + 512], gin = gib[d + 1024];
        float ghr = ghb[d], ghz = ghb[d + 512], ghn = ghb[d + 1024];
        float rr = sigmoid_f(gir + ghr);
        float zz = sigmoid_f(giz + ghz);
        float nn = tanh_f(fmaf(rr, ghn, gin));
        float sp = slots[row * 512 + d];
        s2s[r][d] = fmaf(1.0f - zz, nn, zz * sp);
    }
    __syncthreads();
    // ---- stats of s2
    if (wid < 2) {
        const float4* sr = (const float4*)s2s[wid];
        float4 a = sr[lane], bq = sr[64 + lane];
        float s1 = a.x + a.y + a.z + a.w + bq.x + bq.y + bq.z + bq.w;
        float s2 = a.x*a.x; s2 = fmaf(a.y,a.y,s2); s2 = fmaf(a.z,a.z,s2); s2 = fmaf(a.w,a.w,s2);
        s2 = fmaf(bq.x,bq.x,s2); s2 = fmaf(bq.y,bq.y,s2); s2 = fmaf(bq.z,bq.z,s2); s2 = fmaf(bq.w,bq.w,s2);
#pragma unroll
        for (int off = 32; off > 0; off >>= 1) {
            s1 += __shfl_xor(s1, off, 64);
            s2 += __shfl_xor(s2, off, 64);
        }
        if (lane == 0) {
            float mean = s1 * (1.0f / D_);
            float var  = s2 * (1.0f / D_) - mean * mean;
            stat[wid * 2] = mean;
            stat[wid * 2 + 1] = rsqrtf(var + 1e-5f);
        }
    }
    __syncthreads();
    // ---- h0 = LN_m(s2)
#pragma unroll
    for (int j = 0; j < 2; ++j) {
        int flat = t + j * 512;
        int r = flat >> 9, d = flat & 511;
        t0s[r][d] = fmaf((s2s[r][d] - stat[r * 2]) * stat[r * 2 + 1], ln_m_g[d], ln_m_b[d]);
    }
    __syncthreads();
    // ---- h = relu(h0 @ w1^T + b1)
    {
        const int c = t;
        const float4* wr = (const float4*)(w1 + (size_t)c * 512);
        float a0 = 0.f, a1 = 0.f;
#pragma unroll 8
        for (int k4 = 0; k4 < 128; ++k4) {
            float4 w4 = wr[k4];
            float4 q0 = *(const float4*)&t0s[0][k4 << 2];
            float4 q1 = *(const float4*)&t0s[1][k4 << 2];
            a0 = fmaf(q0.x, w4.x, a0); a0 = fmaf(q0.y, w4.y, a0);
            a0 = fmaf(q0.z, w4.z, a0); a0 = fmaf(q0.w, w4.w, a0);
            a1 = fmaf(q1.x, w4.x, a1); a1 = fmaf(q1.y, w4.y, a1);
            a1 = fmaf(q1.z, w4.z, a1); a1 = fmaf(q1.w, w4.w, a1);
        }
        float bc = b1[c];
        hs[0][c] = fmaxf(a0 + bc, 0.f);
        hs[1][c] = fmaxf(a1 + bc, 0.f);
    }
    __syncthreads();
    // ---- out = s2 + h @ w2^T + b2  (write dst, keep in s2s)
    {
        const int c = t;
        const float4* wr = (const float4*)(w2 + (size_t)c * 512);
        float a0 = 0.f, a1 = 0.f;
#pragma unroll 8
        for (int k4 = 0; k4 < 128; ++k4) {
            float4 w4 = wr[k4];
            float4 q0 = *(const float4*)&hs[0][k4 << 2];
            float4 q1 = *(const float4*)&hs[1][k4 << 2];
            a0 = fmaf(q0.x, w4.x, a0); a0 = fmaf(q0.y, w4.y, a0);
            a0 = fmaf(q0.z, w4.z, a0); a0 = fmaf(q0.w, w4.w, a0);
            a1 = fmaf(q1.x, w4.x, a1); a1 = fmaf(q1.y, w4.y, a1);
            a1 = fmaf(q1.z, w4.z, a1); a1 = fmaf(q1.w, w4.w, a1);
        }
        float bc = b2[c];
        float o0 = s2s[0][c] + a0 + bc;
        float o1 = s2s[1][c] + a1 + bc;
        dst[(size_t)r0 * 512 + c] = o0;
        dst[(size_t)(r0 + 1) * 512 + c] = o1;
        s2s[0][c] = o0;
        s2s[1][c] = o1;
    }
    if (last) return;
    __syncthreads();
    // ---- stats of out
    if (wid < 2) {
        const float4* sr = (const float4*)s2s[wid];
        float4 a = sr[lane], bq = sr[64 + lane];
        float s1 = a.x + a.y + a.z + a.w + bq.x + bq.y + bq.z + bq.w;
        float s2 = a.x*a.x; s2 = fmaf(a.y,a.y,s2); s2 = fmaf(a.z,a.z,s2); s2 = fmaf(a.w,a.w,s2);
        s2 = fmaf(bq.x,bq.x,s2); s2 = fmaf(bq.y,bq.y,s2); s2 = fmaf(bq.z,bq.z,s2); s2 = fmaf(bq.w,bq.w,s2);
#pragma unroll
        for (int off = 32; off > 0; off >>= 1) {
            s1 += __shfl_xor(s1, off, 64);
            s2 += __shfl_xor(s2, off, 64);
        }
        if (lane == 0) {
            float mean = s1 * (1.0f / D_);
            float var  = s2 * (1.0f / D_) - mean * mean;
            stat[wid * 2] = mean;
            stat[wid * 2 + 1] = rsqrtf(var + 1e-5f);
        }
    }
    __syncthreads();
    // ---- sn = LN_s(out)
#pragma unroll
    for (int j = 0; j < 2; ++j) {
        int flat = t + j * 512;
        int r = flat >> 9, d = flat & 511;
        t0s[r][d] = fmaf((s2s[r][d] - stat[r * 2]) * stat[r * 2 + 1], ln_s_g[d], ln_s_b[d]);
    }
    __syncthreads();
    // ---- qk = sn @ wqkT^T
    {
        const int c = t;
        const float4* wr = (const float4*)(wqkT + (size_t)c * 512);
        float a0 = 0.f, a1 = 0.f;
#pragma unroll 8
        for (int k4 = 0; k4 < 128; ++k4) {
            float4 w4 = wr[k4];
            float4 q0 = *(const float4*)&t0s[0][k4 << 2];
            float4 q1 = *(const float4*)&t0s[1][k4 << 2];
            a0 = fmaf(q0.x, w4.x, a0); a0 = fmaf(q0.y, w4.y, a0);
            a0 = fmaf(q0.z, w4.z, a0); a0 = fmaf(q0.w, w4.w, a0);
            a1 = fmaf(q1.x, w4.x, a1); a1 = fmaf(q1.y, w4.y, a1);
            a1 = fmaf(q1.z, w4.z, a1); a1 = fmaf(q1.w, w4.w, a1);
        }
        qkout[(size_t)r0 * 512 + c] = a0;
        qkout[(size_t)(r0 + 1) * 512 + c] = a1;
    }
}

// ---------------------------------------------------------------- launch
extern "C" void kernel_launch(void* const* d_in, const int* in_sizes, int n_in,
                              void* d_out, int out_size, void* d_ws, size_t ws_size,
                              hipStream_t stream) {
    const float* inputs  = (const float*)d_in[0];
    const float* noise   = (const float*)d_in[1];
    const float* mu      = (const float*)d_in[2];
    const float* sg      = (const float*)d_in[3];
    const float* ln_in_g = (const float*)d_in[4];
    const float* ln_in_b = (const float*)d_in[5];
    const float* ln_s_g  = (const float*)d_in[6];
    const float* ln_s_b  = (const float*)d_in[7];
    const float* wq      = (const float*)d_in[8];
    const float* wk      = (const float*)d_in[9];
    const float* wv      = (const float*)d_in[10];
    const float* w_ih    = (const float*)d_in[11];
    const float* w_hh    = (const float*)d_in[12];
    const float* b_ih    = (const float*)d_in[13];
    const float* b_hh    = (const float*)d_in[14];
    const float* ln_m_g  = (const float*)d_in[15];
    const float* ln_m_b  = (const float*)d_in[16];
    const float* w1      = (const float*)d_in[17];
    const float* b1      = (const float*)d_in[18];
    const float* w2      = (const float*)d_in[19];
    const float* b2      = (const float*)d_in[20];

    float* ws = (float*)d_ws;
    const size_t SLOT = (size_t)B_ * S_ * D_;      // 131072
    float* slots = ws;
    float* qk    = ws + SLOT;
    float* u0    = ws + 2 * SLOT;
    float* upd   = ws + 3 * SLOT;
    float* gi    = ws + 4 * SLOT;                  // 393216
    float* gh    = gi + 3 * SLOT;
    float* wqkT  = gh + 3 * SLOT;                  // 262144
    float* stats = wqkT + 2 * SLOT;                // 512
    float* part  = stats + 1024;                   // 32*32*4096

    // WqkT[d][f] = sum_e wk[e][d] * wq[e][f]
    k_gemm<2,0><<<dim3(16, 8), 256, 0, stream>>>(wk, wq, nullptr, nullptr, wqkT,
                                                 512, 512, 512, 0, nullptr, nullptr, nullptr);
    // slots init + LN stats
    k_init<<<64, 256, 0, stream>>>(noise, mu, sg, slots, stats);
    // qk0 = LN_s(slots) @ WqkT^T
    k_gemm<1,1><<<dim3(16, 4), 256, 0, stream>>>(slots, wqkT, nullptr, nullptr, qk,
                                                 256, 512, 512, 0, stats, ln_s_g, ln_s_b);

    for (int it = 0; it < ITERS_; ++it) {
        k_attn<<<dim3(CH, B_), 256, 0, stream>>>(inputs, ln_in_g, ln_in_b, qk, part);
        k_reduce_u0<<<128, 256, 0, stream>>>(part, u0);
        // upd = u0 @ wv^T
        k_gemm<1,0><<<dim3(16, 4), 256, 0, stream>>>(u0, wv, nullptr, nullptr, upd,
                                                     256, 512, 512, 0, nullptr, nullptr, nullptr);
        // gi = upd @ w_ih^T + b_ih ; gh = slots @ w_hh^T + b_hh
        k_gemm<1,0><<<dim3(48, 4), 256, 0, stream>>>(upd, w_ih, b_ih, nullptr, gi,
                                                     256, 1536, 512, 0, nullptr, nullptr, nullptr);
        k_gemm<1,0><<<dim3(48, 4), 256, 0, stream>>>(slots, w_hh, b_hh, nullptr, gh,
                                                     256, 1536, 512, 0, nullptr, nullptr, nullptr);
        int last = (it == ITERS_ - 1);
        float* dst = last ? (float*)d_out : slots;
        k_p2<<<128, 512, 0, stream>>>(gi, gh, slots, w1, b1, w2, b2, wqkT,
                                      ln_m_g, ln_m_b, ln_s_g, ln_s_b, dst, qk, last);
    }
}